// Round 1
// baseline (657.811 us; speedup 1.0000x reference)
//
#include <hip/hip_runtime.h>

// SSIM (skimage default): 7x7 uniform filter, valid crop (pad=3), sample cov.
// Images: 4096x4096 fp32, output region 4090x4090, result = mean(S) scalar.
//
// R1: latency/occupancy fix. ROWS 32->10 (4090 = 409*10 exactly) so every
// strip is full -> steady loop is branch-free and fully unrolled, and the
// grid grows 1024 -> 3272 blocks (~7 waves/SIMD resident at 72 VGPR vs 4
// before). hsums now writes directly into its ring slot (no h[]->ring copy).

#define W_IMG   4096
#define H_IMG   4096
#define OW      4090
#define OH      4090
#define ROWS    10            // output rows per block strip; divides 4090
#define NTHR    256           // threads per block
#define CPB     512           // output columns per block (2 per thread)

__device__ __forceinline__ void hsums(const float* __restrict__ pO,
                                      const float* __restrict__ pT,
                                      float h[10])
{
    // load 8 consecutive floats of each image (8B-aligned: col0 is even)
    float2 a0 = *(const float2*)(pO + 0);
    float2 a1 = *(const float2*)(pO + 2);
    float2 a2 = *(const float2*)(pO + 4);
    float2 a3 = *(const float2*)(pO + 6);
    float2 b0 = *(const float2*)(pT + 0);
    float2 b1 = *(const float2*)(pT + 2);
    float2 b2 = *(const float2*)(pT + 4);
    float2 b3 = *(const float2*)(pT + 6);
    float o0=a0.x,o1=a0.y,o2=a1.x,o3=a1.y,o4=a2.x,o5=a2.y,o6=a3.x,o7=a3.y;
    float t0=b0.x,t1=b0.y,t2=b1.x,t3=b1.y,t4=b2.x,t5=b2.y,t6=b3.x,t7=b3.y;

    float so  = ((o0+o1)+(o2+o3)) + ((o4+o5)+o6);
    float st  = ((t0+t1)+(t2+t3)) + ((t4+t5)+t6);
    float soo = fmaf(o6,o6, fmaf(o5,o5, fmaf(o4,o4, fmaf(o3,o3, fmaf(o2,o2, fmaf(o1,o1, o0*o0))))));
    float stt = fmaf(t6,t6, fmaf(t5,t5, fmaf(t4,t4, fmaf(t3,t3, fmaf(t2,t2, fmaf(t1,t1, t0*t0))))));
    float sot = fmaf(o6,t6, fmaf(o5,t5, fmaf(o4,t4, fmaf(o3,t3, fmaf(o2,t2, fmaf(o1,t1, o0*t0))))));

    h[0] = so;   h[1] = so  - o0    + o7;
    h[2] = st;   h[3] = st  - t0    + t7;
    h[4] = soo;  h[5] = soo - o0*o0 + o7*o7;
    h[6] = stt;  h[7] = stt - t0*t0 + t7*t7;
    h[8] = sot;  h[9] = sot - o0*t0 + o7*t7;
}

__device__ __forceinline__ float ssim_from(const float v[10], int px)
{
    const float m    = 1.0f / 49.0f;
    const float covn = 49.0f / 48.0f;
    const float C1   = 4.0e-4f;   // (0.01*2)^2
    const float C2   = 3.6e-3f;   // (0.03*2)^2
    float so  = v[0+px], st  = v[2+px];
    float soo = v[4+px], stt = v[6+px], sot = v[8+px];
    float ux  = so*m,  uy  = st*m;
    float uxx = soo*m, uyy = stt*m, uxy = sot*m;
    float vx  = covn*(uxx - ux*ux);
    float vy  = covn*(uyy - uy*uy);
    float vxy = covn*(uxy - ux*uy);
    float A1  = 2.0f*ux*uy + C1;
    float A2  = 2.0f*vxy + C2;
    float B1  = (ux*ux + uy*uy) + C1;
    float B2  = (vx + vy) + C2;
    float num = A1*A2;
    float den = B1*B2;
    return num * __builtin_amdgcn_rcpf(den);   // ~1 ulp, far within tolerance
}

__global__ __launch_bounds__(NTHR, 6)
void ssim_main(const float* __restrict__ O, const float* __restrict__ T,
               float* __restrict__ accp)
{
    const int t  = threadIdx.x;
    const int c0 = blockIdx.x * CPB + 2*t;     // first of the 2 output cols
    const int r0 = blockIdx.y * ROWS;          // first output row of strip
    // every strip is full: OH % ROWS == 0

    float acc = 0.0f;

    if (c0 < OW) {  // c0 even, OW even -> both pixels valid together
        const float* pO = O + (size_t)r0 * W_IMG + c0;
        const float* pT = T + (size_t)r0 * W_IMG + c0;

        float ring[7][10];   // 7-row delay line of horizontal sums (regs)
        float v[10];         // running vertical sums over the 7-row window
        #pragma unroll
        for (int q = 0; q < 10; q++) v[q] = 0.0f;

        // warm-up: input rows r0+0 .. r0+5
        #pragma unroll
        for (int i = 0; i < 6; i++) {
            hsums(pO, pT, ring[i]);
            #pragma unroll
            for (int q = 0; q < 10; q++) v[q] += ring[i][q];
            pO += W_IMG; pT += W_IMG;
        }

        // steady: output row j (input row j+6). Fully unrolled, branch-free;
        // ring slot indices are compile-time constants (stays in VGPRs).
        #pragma unroll
        for (int j = 0; j < ROWS; j++) {
            const int snew = (j + 6) % 7;   // slot of arriving row j+6
            const int sold = j % 7;         // slot of departing row j-1... (row j-? = j)
            hsums(pO, pT, ring[snew]);      // write new row's sums in place
            #pragma unroll
            for (int q = 0; q < 10; q++) v[q] += ring[snew][q];
            // window now covers rows [j, j+6]
            acc += ssim_from(v, 0);
            acc += ssim_from(v, 1);
            #pragma unroll
            for (int q = 0; q < 10; q++) v[q] -= ring[sold][q];
            pO += W_IMG; pT += W_IMG;
        }
    }

    // wave(64) shuffle reduction
    #pragma unroll
    for (int off = 32; off; off >>= 1) acc += __shfl_down(acc, off);

    __shared__ float wpart[NTHR / 64];
    if ((t & 63) == 0) wpart[t >> 6] = acc;
    __syncthreads();
    if (t == 0) {
        float s = 0.0f;
        #pragma unroll
        for (int w = 0; w < NTHR / 64; w++) s += wpart[w];
        atomicAdd(accp, s);   // one atomic per block (3272 total)
    }
}

__global__ void ssim_final(const float* __restrict__ accp, float* __restrict__ out)
{
    out[0] = accp[0] * (float)(1.0 / ((double)OW * (double)OH));
}

extern "C" void kernel_launch(void* const* d_in, const int* in_sizes, int n_in,
                              void* d_out, int out_size, void* d_ws, size_t ws_size,
                              hipStream_t stream)
{
    const float* O = (const float*)d_in[0];
    const float* T = (const float*)d_in[1];
    float* out = (float*)d_out;
    float* acc = (float*)d_ws;

    hipMemsetAsync(acc, 0, sizeof(float), stream);   // ws is re-poisoned to 0xAA

    dim3 grid((OW + CPB - 1) / CPB, OH / ROWS);      // (8, 409)
    ssim_main<<<grid, NTHR, 0, stream>>>(O, T, acc);
    ssim_final<<<1, 1, 0, stream>>>(acc, out);
}

// Round 2
// 342.589 us; speedup vs baseline: 1.9201x; 1.9201x over previous
//
#include <hip/hip_runtime.h>

// SSIM (skimage default): 7x7 uniform filter, valid crop (pad=3), sample cov.
// Images: 4096x4096 fp32, output region 4090x4090, result = mean(S) scalar.
//
// R2: keep ROWS=10 (grid 3272 blocks -> occupancy no longer grid-starved),
// but revert __launch_bounds__ to (NTHR, 3). R1's (NTHR, 6) capped VGPRs at
// ~85 and spilled the 70-reg ring to scratch (WRITE_SIZE 1.2 GB, 6x slower).
// The ring MUST stay in VGPRs; cap 170 is the proven-safe setting (72 VGPR
// in R0's chunked variant).

#define W_IMG   4096
#define H_IMG   4096
#define OW      4090
#define OH      4090
#define ROWS    10            // output rows per block strip; divides 4090
#define NTHR    256           // threads per block
#define CPB     512           // output columns per block (2 per thread)

__device__ __forceinline__ void hsums(const float* __restrict__ pO,
                                      const float* __restrict__ pT,
                                      float h[10])
{
    // load 8 consecutive floats of each image (8B-aligned: col0 is even)
    float2 a0 = *(const float2*)(pO + 0);
    float2 a1 = *(const float2*)(pO + 2);
    float2 a2 = *(const float2*)(pO + 4);
    float2 a3 = *(const float2*)(pO + 6);
    float2 b0 = *(const float2*)(pT + 0);
    float2 b1 = *(const float2*)(pT + 2);
    float2 b2 = *(const float2*)(pT + 4);
    float2 b3 = *(const float2*)(pT + 6);
    float o0=a0.x,o1=a0.y,o2=a1.x,o3=a1.y,o4=a2.x,o5=a2.y,o6=a3.x,o7=a3.y;
    float t0=b0.x,t1=b0.y,t2=b1.x,t3=b1.y,t4=b2.x,t5=b2.y,t6=b3.x,t7=b3.y;

    float so  = ((o0+o1)+(o2+o3)) + ((o4+o5)+o6);
    float st  = ((t0+t1)+(t2+t3)) + ((t4+t5)+t6);
    float soo = fmaf(o6,o6, fmaf(o5,o5, fmaf(o4,o4, fmaf(o3,o3, fmaf(o2,o2, fmaf(o1,o1, o0*o0))))));
    float stt = fmaf(t6,t6, fmaf(t5,t5, fmaf(t4,t4, fmaf(t3,t3, fmaf(t2,t2, fmaf(t1,t1, t0*t0))))));
    float sot = fmaf(o6,t6, fmaf(o5,t5, fmaf(o4,t4, fmaf(o3,t3, fmaf(o2,t2, fmaf(o1,t1, o0*t0))))));

    h[0] = so;   h[1] = so  - o0    + o7;
    h[2] = st;   h[3] = st  - t0    + t7;
    h[4] = soo;  h[5] = soo - o0*o0 + o7*o7;
    h[6] = stt;  h[7] = stt - t0*t0 + t7*t7;
    h[8] = sot;  h[9] = sot - o0*t0 + o7*t7;
}

__device__ __forceinline__ float ssim_from(const float v[10], int px)
{
    const float m    = 1.0f / 49.0f;
    const float covn = 49.0f / 48.0f;
    const float C1   = 4.0e-4f;   // (0.01*2)^2
    const float C2   = 3.6e-3f;   // (0.03*2)^2
    float so  = v[0+px], st  = v[2+px];
    float soo = v[4+px], stt = v[6+px], sot = v[8+px];
    float ux  = so*m,  uy  = st*m;
    float uxx = soo*m, uyy = stt*m, uxy = sot*m;
    float vx  = covn*(uxx - ux*ux);
    float vy  = covn*(uyy - uy*uy);
    float vxy = covn*(uxy - ux*uy);
    float A1  = 2.0f*ux*uy + C1;
    float A2  = 2.0f*vxy + C2;
    float B1  = (ux*ux + uy*uy) + C1;
    float B2  = (vx + vy) + C2;
    float num = A1*A2;
    float den = B1*B2;
    return num * __builtin_amdgcn_rcpf(den);   // ~1 ulp, far within tolerance
}

__global__ __launch_bounds__(NTHR, 3)
void ssim_main(const float* __restrict__ O, const float* __restrict__ T,
               float* __restrict__ accp)
{
    const int t  = threadIdx.x;
    const int c0 = blockIdx.x * CPB + 2*t;     // first of the 2 output cols
    const int r0 = blockIdx.y * ROWS;          // first output row of strip
    // every strip is full: OH % ROWS == 0

    float acc = 0.0f;

    if (c0 < OW) {  // c0 even, OW even -> both pixels valid together
        const float* pO = O + (size_t)r0 * W_IMG + c0;
        const float* pT = T + (size_t)r0 * W_IMG + c0;

        float ring[7][10];   // 7-row delay line of horizontal sums (regs)
        float v[10];         // running vertical sums over the 7-row window
        #pragma unroll
        for (int q = 0; q < 10; q++) v[q] = 0.0f;

        // warm-up: input rows r0+0 .. r0+5
        #pragma unroll
        for (int i = 0; i < 6; i++) {
            hsums(pO, pT, ring[i]);
            #pragma unroll
            for (int q = 0; q < 10; q++) v[q] += ring[i][q];
            pO += W_IMG; pT += W_IMG;
        }

        // steady: output row j (input row j+6). Fully unrolled, branch-free;
        // ring slot indices are compile-time constants (stays in VGPRs).
        #pragma unroll
        for (int j = 0; j < ROWS; j++) {
            const int snew = (j + 6) % 7;   // slot of arriving row j+6
            const int sold = j % 7;         // slot of departing row j
            hsums(pO, pT, ring[snew]);      // write new row's sums in place
            #pragma unroll
            for (int q = 0; q < 10; q++) v[q] += ring[snew][q];
            // window now covers rows [j, j+6]
            acc += ssim_from(v, 0);
            acc += ssim_from(v, 1);
            #pragma unroll
            for (int q = 0; q < 10; q++) v[q] -= ring[sold][q];
            pO += W_IMG; pT += W_IMG;
        }
    }

    // wave(64) shuffle reduction
    #pragma unroll
    for (int off = 32; off; off >>= 1) acc += __shfl_down(acc, off);

    __shared__ float wpart[NTHR / 64];
    if ((t & 63) == 0) wpart[t >> 6] = acc;
    __syncthreads();
    if (t == 0) {
        float s = 0.0f;
        #pragma unroll
        for (int w = 0; w < NTHR / 64; w++) s += wpart[w];
        atomicAdd(accp, s);   // one atomic per block (3272 total)
    }
}

__global__ void ssim_final(const float* __restrict__ accp, float* __restrict__ out)
{
    out[0] = accp[0] * (float)(1.0 / ((double)OW * (double)OH));
}

extern "C" void kernel_launch(void* const* d_in, const int* in_sizes, int n_in,
                              void* d_out, int out_size, void* d_ws, size_t ws_size,
                              hipStream_t stream)
{
    const float* O = (const float*)d_in[0];
    const float* T = (const float*)d_in[1];
    float* out = (float*)d_out;
    float* acc = (float*)d_ws;

    hipMemsetAsync(acc, 0, sizeof(float), stream);   // ws is re-poisoned to 0xAA

    dim3 grid((OW + CPB - 1) / CPB, OH / ROWS);      // (8, 409)
    ssim_main<<<grid, NTHR, 0, stream>>>(O, T, acc);
    ssim_final<<<1, 1, 0, stream>>>(acc, out);
}

// Round 4
// 175.654 us; speedup vs baseline: 3.7449x; 1.9504x over previous
//
#include <hip/hip_runtime.h>

// SSIM (skimage default): 7x7 uniform filter, valid crop (pad=3), sample cov.
// Images: 4096x4096 fp32, output region 4090x4090, result = mean(S) scalar.
//
// R4 == R3 resubmit (R3 bench was an infra failure: container died twice,
// no counters). R0's exact loop structure (chunked jb+=7, h[10]+copy,
// RUNTIME rows_in guards) with ROWS=10 (grid 8x409 = 3272 blocks). History:
//  - R0 (ROWS=32, this body): 72 VGPR, zero spill, 92 us, but occupancy 24%
//    (grid-starved at 1024 blocks).
//  - R1/R2 (fully-unrolled steady loop): compiler hoisted loads across rows,
//    live ranges exploded, ring spilled to scratch (WRITE_SIZE 0.4-1.2 GB).
// The runtime guards `j < rows_in` are load-bearing: they fence the scheduler
// into 7-row regions and keep the ring register-resident. Do not replace
// rows_in with a compile-time constant.

#define W_IMG   4096
#define H_IMG   4096
#define OW      4090
#define OH      4090
#define ROWS    10            // output rows per block strip; divides 4090
#define NTHR    256           // threads per block
#define CPB     512           // output columns per block (2 per thread)

__device__ __forceinline__ void hsums(const float* __restrict__ pO,
                                      const float* __restrict__ pT,
                                      float h[10])
{
    // load 8 consecutive floats of each image (8B-aligned: col0 is even)
    float2 a0 = *(const float2*)(pO + 0);
    float2 a1 = *(const float2*)(pO + 2);
    float2 a2 = *(const float2*)(pO + 4);
    float2 a3 = *(const float2*)(pO + 6);
    float2 b0 = *(const float2*)(pT + 0);
    float2 b1 = *(const float2*)(pT + 2);
    float2 b2 = *(const float2*)(pT + 4);
    float2 b3 = *(const float2*)(pT + 6);
    float o0=a0.x,o1=a0.y,o2=a1.x,o3=a1.y,o4=a2.x,o5=a2.y,o6=a3.x,o7=a3.y;
    float t0=b0.x,t1=b0.y,t2=b1.x,t3=b1.y,t4=b2.x,t5=b2.y,t6=b3.x,t7=b3.y;

    float so  = ((o0+o1)+(o2+o3)) + ((o4+o5)+o6);
    float st  = ((t0+t1)+(t2+t3)) + ((t4+t5)+t6);
    float soo = fmaf(o6,o6, fmaf(o5,o5, fmaf(o4,o4, fmaf(o3,o3, fmaf(o2,o2, fmaf(o1,o1, o0*o0))))));
    float stt = fmaf(t6,t6, fmaf(t5,t5, fmaf(t4,t4, fmaf(t3,t3, fmaf(t2,t2, fmaf(t1,t1, t0*t0))))));
    float sot = fmaf(o6,t6, fmaf(o5,t5, fmaf(o4,t4, fmaf(o3,t3, fmaf(o2,t2, fmaf(o1,t1, o0*t0))))));

    h[0] = so;   h[1] = so  - o0    + o7;
    h[2] = st;   h[3] = st  - t0    + t7;
    h[4] = soo;  h[5] = soo - o0*o0 + o7*o7;
    h[6] = stt;  h[7] = stt - t0*t0 + t7*t7;
    h[8] = sot;  h[9] = sot - o0*t0 + o7*t7;
}

__device__ __forceinline__ float ssim_from(const float v[10], int px)
{
    const float m    = 1.0f / 49.0f;
    const float covn = 49.0f / 48.0f;
    const float C1   = 4.0e-4f;   // (0.01*2)^2
    const float C2   = 3.6e-3f;   // (0.03*2)^2
    float so  = v[0+px], st  = v[2+px];
    float soo = v[4+px], stt = v[6+px], sot = v[8+px];
    float ux  = so*m,  uy  = st*m;
    float uxx = soo*m, uyy = stt*m, uxy = sot*m;
    float vx  = covn*(uxx - ux*ux);
    float vy  = covn*(uyy - uy*uy);
    float vxy = covn*(uxy - ux*uy);
    float A1  = 2.0f*ux*uy + C1;
    float A2  = 2.0f*vxy + C2;
    float B1  = (ux*ux + uy*uy) + C1;
    float B2  = (vx + vy) + C2;
    float num = A1*A2;
    float den = B1*B2;
    return num * __builtin_amdgcn_rcpf(den);   // ~1 ulp, far within tolerance
}

__global__ __launch_bounds__(NTHR, 3)
void ssim_main(const float* __restrict__ O, const float* __restrict__ T,
               float* __restrict__ accp)
{
    const int t  = threadIdx.x;
    const int c0 = blockIdx.x * CPB + 2*t;     // first of the 2 output cols
    const int r0 = blockIdx.y * ROWS;          // first output row of strip
    const int rows_in = min(ROWS, OH - r0);    // runtime to the compiler!

    float acc = 0.0f;

    if (c0 < OW) {  // c0 even, OW even -> both pixels valid together
        const float* baseO = O + (size_t)r0 * W_IMG + c0;
        const float* baseT = T + (size_t)r0 * W_IMG + c0;

        float ring[7][10];   // 7-row delay line of horizontal sums (regs)
        float v[10];         // running vertical sums over the 7-row window
        #pragma unroll
        for (int q = 0; q < 10; q++) v[q] = 0.0f;

        // warm-up: input rows 0..5
        #pragma unroll
        for (int i = 0; i < 6; i++) {
            float h[10];
            hsums(baseO + (size_t)i * W_IMG, baseT + (size_t)i * W_IMG, h);
            #pragma unroll
            for (int q = 0; q < 10; q++) { v[q] += h[q]; ring[i][q] = h[q]; }
        }

        // steady: output row j (input row i = j+6); chunked by 7 so ring
        // slot indices are compile-time constants (stays in VGPRs).
        for (int jb = 0; jb < ROWS; jb += 7) {
            #pragma unroll
            for (int u = 0; u < 7; u++) {
                const int j = jb + u;
                if (j < rows_in) {
                    const int i = j + 6;
                    float h[10];
                    hsums(baseO + (size_t)i * W_IMG,
                          baseT + (size_t)i * W_IMG, h);
                    #pragma unroll
                    for (int q = 0; q < 10; q++) v[q] += h[q];
                    // window now covers rows [j, j+6]
                    acc += ssim_from(v, 0);
                    acc += ssim_from(v, 1);
                    // drop row i-6 (slot (i+1)%7 == u), store row i (slot i%7)
                    #pragma unroll
                    for (int q = 0; q < 10; q++) {
                        v[q] -= ring[u][q];
                        ring[(u + 6) % 7][q] = h[q];
                    }
                }
            }
        }
    }

    // wave(64) shuffle reduction
    #pragma unroll
    for (int off = 32; off; off >>= 1) acc += __shfl_down(acc, off);

    __shared__ float wpart[NTHR / 64];
    if ((t & 63) == 0) wpart[t >> 6] = acc;
    __syncthreads();
    if (t == 0) {
        float s = 0.0f;
        #pragma unroll
        for (int w = 0; w < NTHR / 64; w++) s += wpart[w];
        atomicAdd(accp, s);   // one atomic per block (3272 total)
    }
}

__global__ void ssim_final(const float* __restrict__ accp, float* __restrict__ out)
{
    out[0] = accp[0] * (float)(1.0 / ((double)OW * (double)OH));
}

extern "C" void kernel_launch(void* const* d_in, const int* in_sizes, int n_in,
                              void* d_out, int out_size, void* d_ws, size_t ws_size,
                              hipStream_t stream)
{
    const float* O = (const float*)d_in[0];
    const float* T = (const float*)d_in[1];
    float* out = (float*)d_out;
    float* acc = (float*)d_ws;

    hipMemsetAsync(acc, 0, sizeof(float), stream);   // ws is re-poisoned to 0xAA

    dim3 grid((OW + CPB - 1) / CPB, OH / ROWS);      // (8, 409)
    ssim_main<<<grid, NTHR, 0, stream>>>(O, T, acc);
    ssim_final<<<1, 1, 0, stream>>>(acc, out);
}

// Round 5
// 174.011 us; speedup vs baseline: 3.7803x; 1.0094x over previous
//
#include <hip/hip_runtime.h>

// SSIM (skimage default): 7x7 uniform filter, valid crop (pad=3), sample cov.
// Images: 4096x4096 fp32, output region 4090x4090, result = mean(S) scalar.
//
// R5: keep R0/R4's proven loop skeleton (chunked jb+=7, h[10]+copy, RUNTIME
// rows_in guards — load-bearing: fences the scheduler, keeps ring in VGPRs;
// R1/R2 spilled 0.4-1.2GB without it). Three local changes:
//  - ROWS 10->16: warm-up amortization 1.6x -> 1.375x (-11% VALU work);
//    grid 8x256=2048 blocks (8/CU, still above the 4/CU starvation seen in R0).
//  - hsums loads: 16x float2 -> 8x 8B-aligned float4 (c0 even; aligned(8)
//    attribute keeps the compiler honest). Halves VMEM instr count.
//  - ssim epilogue: combine the 2 pixels over one v_rcp_f32 (quarter-rate op):
//    n0/d0+n1/d1 = (n0*d1+n1*d0)*rcp(d0*d1).
// History: R4 = 74.5us, VGPR 72, VALUBusy 54%, occupancy-counter ~28%, no
// spill. Falsifier for R5: VGPR>84 or WRITE_SIZE>10MB -> revert piecewise.

#define W_IMG   4096
#define H_IMG   4096
#define OW      4090
#define OH      4090
#define ROWS    16            // output rows per block strip (tail guarded)
#define NTHR    256           // threads per block
#define CPB     512           // output columns per block (2 per thread)

typedef float f4 __attribute__((ext_vector_type(4), aligned(8)));

__device__ __forceinline__ void hsums(const float* __restrict__ pO,
                                      const float* __restrict__ pT,
                                      float h[10])
{
    // load 8 consecutive floats of each image; base is 8B-aligned (c0 even)
    f4 a0 = *(const f4*)(pO + 0);
    f4 a1 = *(const f4*)(pO + 4);
    f4 b0 = *(const f4*)(pT + 0);
    f4 b1 = *(const f4*)(pT + 4);
    float o0=a0.x,o1=a0.y,o2=a0.z,o3=a0.w,o4=a1.x,o5=a1.y,o6=a1.z,o7=a1.w;
    float t0=b0.x,t1=b0.y,t2=b0.z,t3=b0.w,t4=b1.x,t5=b1.y,t6=b1.z,t7=b1.w;

    float so  = ((o0+o1)+(o2+o3)) + ((o4+o5)+o6);
    float st  = ((t0+t1)+(t2+t3)) + ((t4+t5)+t6);
    float soo = fmaf(o6,o6, fmaf(o5,o5, fmaf(o4,o4, fmaf(o3,o3, fmaf(o2,o2, fmaf(o1,o1, o0*o0))))));
    float stt = fmaf(t6,t6, fmaf(t5,t5, fmaf(t4,t4, fmaf(t3,t3, fmaf(t2,t2, fmaf(t1,t1, t0*t0))))));
    float sot = fmaf(o6,t6, fmaf(o5,t5, fmaf(o4,t4, fmaf(o3,t3, fmaf(o2,t2, fmaf(o1,t1, o0*t0))))));

    h[0] = so;   h[1] = so  - o0    + o7;
    h[2] = st;   h[3] = st  - t0    + t7;
    h[4] = soo;  h[5] = soo - o0*o0 + o7*o7;
    h[6] = stt;  h[7] = stt - t0*t0 + t7*t7;
    h[8] = sot;  h[9] = sot - o0*t0 + o7*t7;
}

__device__ __forceinline__ void ssim_nd(const float v[10], int px,
                                        float& num, float& den)
{
    const float m    = 1.0f / 49.0f;
    const float covn = 49.0f / 48.0f;
    const float C1   = 4.0e-4f;   // (0.01*2)^2
    const float C2   = 3.6e-3f;   // (0.03*2)^2
    float so  = v[0+px], st  = v[2+px];
    float soo = v[4+px], stt = v[6+px], sot = v[8+px];
    float ux  = so*m,  uy  = st*m;
    float uxx = soo*m, uyy = stt*m, uxy = sot*m;
    float vx  = covn*(uxx - ux*ux);
    float vy  = covn*(uyy - uy*uy);
    float vxy = covn*(uxy - ux*uy);
    float A1  = 2.0f*ux*uy + C1;
    float A2  = 2.0f*vxy + C2;
    float B1  = (ux*ux + uy*uy) + C1;
    float B2  = (vx + vy) + C2;
    num = A1*A2;
    den = B1*B2;
}

__global__ __launch_bounds__(NTHR, 3)
void ssim_main(const float* __restrict__ O, const float* __restrict__ T,
               float* __restrict__ accp)
{
    const int t  = threadIdx.x;
    const int c0 = blockIdx.x * CPB + 2*t;     // first of the 2 output cols
    const int r0 = blockIdx.y * ROWS;          // first output row of strip
    const int rows_in = min(ROWS, OH - r0);    // runtime to the compiler!

    float acc = 0.0f;

    if (c0 < OW) {  // c0 even, OW even -> both pixels valid together
        const float* baseO = O + (size_t)r0 * W_IMG + c0;
        const float* baseT = T + (size_t)r0 * W_IMG + c0;

        float ring[7][10];   // 7-row delay line of horizontal sums (regs)
        float v[10];         // running vertical sums over the 7-row window
        #pragma unroll
        for (int q = 0; q < 10; q++) v[q] = 0.0f;

        // warm-up: input rows 0..5
        #pragma unroll
        for (int i = 0; i < 6; i++) {
            float h[10];
            hsums(baseO + (size_t)i * W_IMG, baseT + (size_t)i * W_IMG, h);
            #pragma unroll
            for (int q = 0; q < 10; q++) { v[q] += h[q]; ring[i][q] = h[q]; }
        }

        // steady: output row j (input row i = j+6); chunked by 7 so ring
        // slot indices are compile-time constants (stays in VGPRs).
        for (int jb = 0; jb < ROWS; jb += 7) {
            #pragma unroll
            for (int u = 0; u < 7; u++) {
                const int j = jb + u;
                if (j < rows_in) {
                    const int i = j + 6;
                    float h[10];
                    hsums(baseO + (size_t)i * W_IMG,
                          baseT + (size_t)i * W_IMG, h);
                    #pragma unroll
                    for (int q = 0; q < 10; q++) v[q] += h[q];
                    // window now covers rows [j, j+6]
                    float n0, d0, n1, d1;
                    ssim_nd(v, 0, n0, d0);
                    ssim_nd(v, 1, n1, d1);
                    // one quarter-rate rcp for both pixels
                    acc = fmaf(fmaf(n0, d1, n1*d0),
                               __builtin_amdgcn_rcpf(d0*d1), acc);
                    // drop row i-6 (slot (i+1)%7 == u), store row i (slot i%7)
                    #pragma unroll
                    for (int q = 0; q < 10; q++) {
                        v[q] -= ring[u][q];
                        ring[(u + 6) % 7][q] = h[q];
                    }
                }
            }
        }
    }

    // wave(64) shuffle reduction
    #pragma unroll
    for (int off = 32; off; off >>= 1) acc += __shfl_down(acc, off);

    __shared__ float wpart[NTHR / 64];
    if ((t & 63) == 0) wpart[t >> 6] = acc;
    __syncthreads();
    if (t == 0) {
        float s = 0.0f;
        #pragma unroll
        for (int w = 0; w < NTHR / 64; w++) s += wpart[w];
        atomicAdd(accp, s);   // one atomic per block (2048 total)
    }
}

__global__ void ssim_final(const float* __restrict__ accp, float* __restrict__ out)
{
    out[0] = accp[0] * (float)(1.0 / ((double)OW * (double)OH));
}

extern "C" void kernel_launch(void* const* d_in, const int* in_sizes, int n_in,
                              void* d_out, int out_size, void* d_ws, size_t ws_size,
                              hipStream_t stream)
{
    const float* O = (const float*)d_in[0];
    const float* T = (const float*)d_in[1];
    float* out = (float*)d_out;
    float* acc = (float*)d_ws;

    hipMemsetAsync(acc, 0, sizeof(float), stream);   // ws is re-poisoned to 0xAA

    dim3 grid((OW + CPB - 1) / CPB, (OH + ROWS - 1) / ROWS);  // (8, 256)
    ssim_main<<<grid, NTHR, 0, stream>>>(O, T, acc);
    ssim_final<<<1, 1, 0, stream>>>(acc, out);
}